// Round 2
// baseline (294.184 us; speedup 1.0000x reference)
//
#include <hip/hip_runtime.h>
#include <hip/hip_bf16.h>

// Problem constants
#define Bb 8
#define Ss 8192
#define Dd 256             // DIN == DH == 256
#define Mm (Bb * Ss)       // 65536 rows
#define Nn 512             // 2*DH output cols of the GEMM
#define NCHUNK 128
#define CLEN (Ss / NCHUNK) // 64
#define NSEG 8             // segments of 16 chunks for the combine scan
#define SEGC (NCHUNK / NSEG)

typedef __hip_bfloat16 bf16;
typedef __attribute__((ext_vector_type(8))) short short8;
typedef __attribute__((ext_vector_type(4))) float f32x4;

__device__ __forceinline__ void load_lds16(const void* g, void* l) {
  __builtin_amdgcn_global_load_lds(
      (const __attribute__((address_space(1))) void*)g,
      (__attribute__((address_space(3))) void*)l, 16, 0, 0);
}

template <int N>
__device__ __forceinline__ void wait_vmcnt() {
  if constexpr (N == 0)
    asm volatile("s_waitcnt vmcnt(0)" ::: "memory");
  else if constexpr (N == 4)
    asm volatile("s_waitcnt vmcnt(4)" ::: "memory");
  else
    static_assert(N == 0 || N == 4, "unsupported vmcnt");
}

// ---------------------------------------------------------------------------
// f32 -> bf16 convert (weights + X)
// ---------------------------------------------------------------------------
__global__ __launch_bounds__(256) void cvt_f32_bf16(const float* __restrict__ in,
                                                    bf16* __restrict__ out,
                                                    long n4) {
  long i = (long)blockIdx.x * blockDim.x + threadIdx.x;
  if (i >= n4) return;
  const float4 v = ((const float4*)in)[i];
  union { ushort4 u; bf16 h[4]; } o;
  o.h[0] = __float2bfloat16(v.x);
  o.h[1] = __float2bfloat16(v.y);
  o.h[2] = __float2bfloat16(v.z);
  o.h[3] = __float2bfloat16(v.w);
  ((ushort4*)out)[i] = o.u;
}

// ---------------------------------------------------------------------------
// Pointwise: a = sigmoid(-gate), v = sigmoid(gate) * g(hidden)
// ---------------------------------------------------------------------------
__device__ __forceinline__ void av_from_gh(float gate, float hid, float& a,
                                           float& v) {
  gate = fminf(fmaxf(gate, -20.f), 20.f);
  float eg = __expf(gate);
  a = 1.f / (1.f + eg);   // sigmoid(-gate) = 1 - z
  float z = eg * a;       // sigmoid(gate)
  // branchless g(): hid>=0 ? hid+0.5 : sigmoid(hid)
  float eh = __expf(fminf(fmaxf(hid, -20.f), 0.f));
  float sig = eh / (1.f + eh);
  float gfun = (hid >= 0.f) ? (hid + 0.5f) : sig;
  v = z * gfun;
}

__device__ __forceinline__ unsigned pack_av(float a, float v) {
  union { bf16 h[2]; unsigned u; } o;
  o.h[0] = __float2bfloat16(a);
  o.h[1] = __float2bfloat16(v);
  return o.u;
}

// ---------------------------------------------------------------------------
// Fused GEMM + bias + pointwise + per-chunk scan summaries. bf16 A only.
//
// v3: bf16 X (pre-converted) -> A-LDS halves (32 KB total, 5 blocks/CU),
// fragA is a single ds_read_b128 (no f32->bf16 in-loop conversion).
// All staging/fragment addresses hoisted out of the (fully unrolled) K-loop.
// Counted-vmcnt depth-2 pipeline; XCD-bijective block swizzle.
//
//   block (cb, bt): rows [bt*128,+128) = 2 scan chunks; paired channels
//   d in [cb*64,+64): GEMM cols = gate d and hidden d+256.
// ---------------------------------------------------------------------------
__global__ __launch_bounds__(256, 5) void gemm_av_fused(
    const bf16* __restrict__ X, const bf16* __restrict__ W,
    const float* __restrict__ bias, unsigned* __restrict__ AV,
    float2* __restrict__ AVs) {
  __shared__ __align__(16) char sm[32768];
  bf16* Ab[2] = {(bf16*)sm, (bf16*)(sm + 8192)};
  bf16* Bbf[2] = {(bf16*)(sm + 16384), (bf16*)(sm + 24576)};
  unsigned* Ts = (unsigned*)sm;  // post-K-loop overlay: [64 t][65] u32

  const int tid = threadIdx.x;
  const int w = tid >> 6;
  const int l = tid & 63;
  const int fl = l & 15;
  const int q = l >> 4;

  // XCD-bijective swizzle: xcd owns lin [xcd*256,+256) = bt in [xcd*64,+64)
  const int id = blockIdx.x;
  const int lin = ((id & 7) << 8) | (id >> 3);
  const int cb = lin & 3;              // paired-channel block 0..3
  const int bt = lin >> 2;             // M-tile 0..511
  const long rowBase = (long)bt * 128;
  const int wrow = (w >> 1) * 64;
  const int wc = (w & 1) * 32;

  // ---- staging constants (hoisted): LDS chunk L holds k-chunk (L&3)^swz(row)
  const bf16* aSrc[2];
  const bf16* bSrc[2];
  int sDst[2];
#pragma unroll
  for (int c = 0; c < 2; c++) {
    const int L = c * 256 + tid;
    const int row = L >> 2;                      // 0..127
    const int kc = (L & 3) ^ ((row >> 1) & 3);   // 8-bf16 chunk
    aSrc[c] = X + (rowBase + row) * 256 + kc * 8;
    const int grow = (row < 64) ? (cb * 64 + row) : (192 + cb * 64 + row);
    bSrc[c] = W + (long)grow * 256 + kc * 8;
    sDst[c] = (c * 256 + w * 64) * 16;  // wave-uniform base; HW adds lane*16
  }
  auto stage = [&](int bi, int ks) {
#pragma unroll
    for (int c = 0; c < 2; c++)
      load_lds16(aSrc[c] + ks * 32, (char*)Ab[bi] + sDst[c]);
#pragma unroll
    for (int c = 0; c < 2; c++)
      load_lds16(bSrc[c] + ks * 32, (char*)Bbf[bi] + sDst[c]);
  };

  // ---- fragment LDS offsets (hoisted, swizzle-matched, conflict-free)
  int aOff[4], bOff[4];
#pragma unroll
  for (int mt = 0; mt < 4; mt++) {
    const int row = wrow + 16 * mt + fl;
    aOff[mt] = row * 32 + (q ^ ((row >> 1) & 3)) * 8;
  }
#pragma unroll
  for (int nt = 0; nt < 4; nt++) {
    const int row =
        (nt < 2) ? (wc + 16 * nt + fl) : (64 + wc + 16 * (nt - 2) + fl);
    bOff[nt] = row * 32 + (q ^ ((row >> 1) & 3)) * 8;
  }

  f32x4 acc[4][4];
#pragma unroll
  for (int i = 0; i < 4; i++)
#pragma unroll
    for (int j = 0; j < 4; j++) acc[i][j] = (f32x4)0.0f;

  // ---- K-loop: depth-2 prefetch, counted vmcnt (never drained in-loop)
  stage(0, 0);
  stage(1, 1);
#pragma unroll
  for (int ks = 0; ks < 8; ks++) {
    const int bi = ks & 1;
    if (ks < 7)
      wait_vmcnt<4>();   // own stage-ks (oldest 4) retired -> LDS written
    else
      wait_vmcnt<0>();   // last tile: drain
    __builtin_amdgcn_s_barrier();          // everyone's stage-ks landed
    __builtin_amdgcn_sched_barrier(0);     // keep ds_reads behind the barrier
    short8 af[4], bf_[4];
#pragma unroll
    for (int mt = 0; mt < 4; mt++)
      af[mt] = *(const short8*)((const bf16*)Ab[bi] + aOff[mt]);
#pragma unroll
    for (int nt = 0; nt < 4; nt++)
      bf_[nt] = *(const short8*)((const bf16*)Bbf[bi] + bOff[nt]);
#pragma unroll
    for (int mt = 0; mt < 4; mt++)
#pragma unroll
      for (int nt = 0; nt < 4; nt++)
        acc[mt][nt] = __builtin_amdgcn_mfma_f32_16x16x32_bf16(
            af[mt], bf_[nt], acc[mt][nt], 0, 0, 0);
    asm volatile("s_waitcnt lgkmcnt(0)" ::: "memory");  // my reads of cur done
    __builtin_amdgcn_s_barrier();                       // all reads of cur done
    __builtin_amdgcn_sched_barrier(0);                  // pin stage after bar
    if (ks < 6) stage(bi, ks + 2);  // overwrite cur buffer for step ks+2
  }

  // ---- Epilogue: bias + pointwise + pack; AV global stores
  float bg[2], bh[2];
#pragma unroll
  for (int p = 0; p < 2; p++) {
    const int d = cb * 64 + wc + 16 * p + fl;
    bg[p] = bias[d];
    bh[p] = bias[256 + d];
  }
  unsigned pk[4][2][4];
#pragma unroll
  for (int mt = 0; mt < 4; mt++) {
#pragma unroll
    for (int p = 0; p < 2; p++) {
      const int d = cb * 64 + wc + 16 * p + fl;
      const long r0 = rowBase + wrow + 16 * mt + q * 4;
#pragma unroll
      for (int r = 0; r < 4; r++) {
        float a, v;
        av_from_gh(acc[mt][p][r] + bg[p], acc[mt][p + 2][r] + bh[p], a, v);
        pk[mt][p][r] = pack_av(a, v);
        AV[(r0 + r) * 256 + d] = pk[mt][p][r];
      }
    }
  }

  // ---- Per-chunk scan summaries, two 64-row halves through LDS transpose
#pragma unroll
  for (int h = 0; h < 2; h++) {
    if ((w >> 1) == h) {
#pragma unroll
      for (int mt = 0; mt < 4; mt++)
#pragma unroll
        for (int p = 0; p < 2; p++)
#pragma unroll
          for (int r = 0; r < 4; r++)
            Ts[(16 * mt + 4 * q + r) * 65 + wc + 16 * p + fl] = pk[mt][p][r];
    }
    __syncthreads();
    if (tid < 64) {
      float A = 1.f, H = 0.f;
#pragma unroll 8
      for (int t = 0; t < 64; t++) {
        const unsigned p = Ts[t * 65 + tid];
        const float a = __uint_as_float((p & 0xffffu) << 16);
        const float v = __uint_as_float(p & 0xffff0000u);
        A *= a;
        H = a * H + v;
      }
      const long cg = (long)(bt >> 6) * NCHUNK + ((bt & 63) << 1) + h;
      AVs[cg * 256 + cb * 64 + tid] = make_float2(A, H);
    }
    __syncthreads();
  }
}

// ---------------------------------------------------------------------------
// Combine pass 1: per-segment composite (16 chunks). grid = Bb*NSEG blocks.
// ---------------------------------------------------------------------------
__global__ __launch_bounds__(256) void seg_reduce(
    const float2* __restrict__ AVs, float2* __restrict__ Seg) {
  const int d = threadIdx.x;
  const int b = blockIdx.x >> 3;
  const int s = blockIdx.x & 7;
  float A = 1.f, H = 0.f;
#pragma unroll
  for (int j = 0; j < SEGC; j++) {
    const float2 av = AVs[((long)b * NCHUNK + s * SEGC + j) * 256 + d];
    H = av.x * H + av.y;
    A *= av.x;
  }
  Seg[(b * NSEG + s) * 256 + d] = make_float2(A, H);
}

// ---------------------------------------------------------------------------
// Combine pass 2: serial scan over NSEG segments. grid = Bb blocks.
// ---------------------------------------------------------------------------
__global__ __launch_bounds__(256) void seg_scan(
    const float2* __restrict__ Seg, float* __restrict__ Hseg) {
  const int d = threadIdx.x;
  const int b = blockIdx.x;
  float h = 0.5f;  // h0 = g(0) = 0.5
#pragma unroll
  for (int s = 0; s < NSEG; s++) {
    Hseg[(b * NSEG + s) * 256 + d] = h;
    const float2 sv = Seg[(b * NSEG + s) * 256 + d];
    h = sv.x * h + sv.y;
  }
}

// ---------------------------------------------------------------------------
// Pass C: final scan. Prologue walks <=15 chunk summaries from the segment
// start to this block's chunk, then the CLEN element scan.
// WRITE_BF16 ? bf16 hidden stream (layer0 -> X1) : f32 (layer1 -> out)
// ---------------------------------------------------------------------------
template <bool WRITE_BF16>
__global__ __launch_bounds__(256) void scan_final(
    const unsigned* __restrict__ AV, const float2* __restrict__ AVs,
    const float* __restrict__ Hseg, bf16* __restrict__ OutB,
    float* __restrict__ OutF, float* __restrict__ Hlast) {
  const int d = threadIdx.x;
  const int c = blockIdx.x % NCHUNK;
  const int b = blockIdx.x / NCHUNK;
  const int s = c >> 4;
  float h = Hseg[(b * NSEG + s) * 256 + d];
  for (int j = s * SEGC; j < c; j++) {
    const float2 av = AVs[((long)b * NCHUNK + j) * 256 + d];
    h = av.x * h + av.y;
  }
  long base = ((long)b * Ss + (long)c * CLEN) * 256 + d;
#pragma unroll 8
  for (int t = 0; t < CLEN; t++) {
    const unsigned p = AV[base];
    const float a = __uint_as_float((p & 0xffffu) << 16);
    const float v = __uint_as_float(p & 0xffff0000u);
    h = a * h + v;
    if (WRITE_BF16)
      OutB[base] = __float2bfloat16(h);
    else
      OutF[base] = h;
    base += 256;
  }
  if (c == NCHUNK - 1) Hlast[b * 256 + d] = h;
}

// ---------------------------------------------------------------------------
extern "C" void kernel_launch(void* const* d_in, const int* in_sizes, int n_in,
                              void* d_out, int out_size, void* d_ws,
                              size_t ws_size, hipStream_t stream) {
  const float* x = (const float*)d_in[0];
  const float* W0f = (const float*)d_in[1];
  const float* b0 = (const float*)d_in[2];
  const float* W1f = (const float*)d_in[3];
  const float* b1 = (const float*)d_in[4];

  float* outF = (float*)d_out;              // out1 (f32), Mm*256 elements
  float* hlast = outF + (long)Mm * 256;     // h: (2,8,1,256) f32
  // d_out's 64 MiB doubles as bf16 scratch: X0b in [0,32MB), X1b in [32,64MB).
  // Both are dead before the final f32 out-write overwrites them.
  bf16* X0b = (bf16*)d_out;
  bf16* X1b = (bf16*)d_out + (long)Mm * 256;

  char* ws = (char*)d_ws;
  unsigned* AV = (unsigned*)ws;                      // Mm*256 u32 = 64 MiB
  bf16* W0b = (bf16*)(ws + (long)Mm * 256 * 4);      // 512*256 bf16
  bf16* W1b = W0b + (long)Nn * Dd;
  float2* AVs = (float2*)(W1b + (long)Nn * Dd);      // [Bb*NCHUNK][256] = 2 MiB
  float2* Seg = AVs + (long)Bb * NCHUNK * 256;       // [Bb*NSEG][256] = 128 KiB
  float* Hseg = (float*)(Seg + (long)Bb * NSEG * 256);  // 64 KiB

  const dim3 gemmGrid(2048);  // 1-D, XCD-bijective swizzle decoded in-kernel
  const dim3 blk(256);

  // Convert weights + X to bf16
  {
    const long n4w = (long)Nn * Dd / 4;
    cvt_f32_bf16<<<dim3((n4w + 255) / 256), blk, 0, stream>>>(W0f, W0b, n4w);
    cvt_f32_bf16<<<dim3((n4w + 255) / 256), blk, 0, stream>>>(W1f, W1b, n4w);
    const long n4x = (long)Mm * 256 / 4;
    cvt_f32_bf16<<<dim3((n4x + 255) / 256), blk, 0, stream>>>(x, X0b, n4x);
  }

  // Layer 0
  gemm_av_fused<<<gemmGrid, blk, 0, stream>>>(X0b, W0b, b0, AV, AVs);
  seg_reduce<<<dim3(Bb * NSEG), blk, 0, stream>>>(AVs, Seg);
  seg_scan<<<dim3(Bb), blk, 0, stream>>>(Seg, Hseg);
  scan_final<true><<<dim3(Bb * NCHUNK), blk, 0, stream>>>(AV, AVs, Hseg, X1b,
                                                          nullptr, hlast);

  // Layer 1
  gemm_av_fused<<<gemmGrid, blk, 0, stream>>>(X1b, W1b, b1, AV, AVs);
  seg_reduce<<<dim3(Bb * NSEG), blk, 0, stream>>>(AVs, Seg);
  seg_scan<<<dim3(Bb), blk, 0, stream>>>(Seg, Hseg);
  scan_final<false><<<dim3(Bb * NCHUNK), blk, 0, stream>>>(
      AV, AVs, Hseg, nullptr, outF, hlast + Bb * 256);
}

// Round 3
// 277.472 us; speedup vs baseline: 1.0602x; 1.0602x over previous
//
#include <hip/hip_runtime.h>
#include <hip/hip_bf16.h>

// Problem constants
#define Bb 8
#define Ss 8192
#define Dd 256             // DIN == DH == 256
#define Mm (Bb * Ss)       // 65536 rows
#define Nn 512             // 2*DH output cols of the GEMM
#define NCHUNK 128
#define CLEN (Ss / NCHUNK) // 64
#define TSP 68             // Ts row stride (u32): 64 + 4 pad, 16B-aligned rows

typedef __hip_bfloat16 bf16;
typedef __attribute__((ext_vector_type(8))) short short8;
typedef __attribute__((ext_vector_type(4))) float f32x4;

__device__ __forceinline__ void load_lds16(const void* g, void* l) {
  __builtin_amdgcn_global_load_lds(
      (const __attribute__((address_space(1))) void*)g,
      (__attribute__((address_space(3))) void*)l, 16, 0, 0);
}

template <int N>
__device__ __forceinline__ void wait_vmcnt() {
  if constexpr (N == 0)
    asm volatile("s_waitcnt vmcnt(0)" ::: "memory");
  else if constexpr (N == 4)
    asm volatile("s_waitcnt vmcnt(4)" ::: "memory");
  else if constexpr (N == 6)
    asm volatile("s_waitcnt vmcnt(6)" ::: "memory");
  else
    static_assert(N == 0 || N == 4 || N == 6, "unsupported vmcnt");
}

// ---------------------------------------------------------------------------
// f32 -> bf16 convert, both weight matrices in one launch (256 blocks)
// ---------------------------------------------------------------------------
__global__ __launch_bounds__(256) void cvt_weights(
    const float* __restrict__ inA, const float* __restrict__ inB,
    bf16* __restrict__ outA, bf16* __restrict__ outB, long n4each) {
  long i = (long)blockIdx.x * blockDim.x + threadIdx.x;
  const float* in = inA;
  bf16* out = outA;
  if (i >= n4each) {
    in = inB;
    out = outB;
    i -= n4each;
  }
  if (i >= n4each) return;
  const float4 v = ((const float4*)in)[i];
  union { ushort4 u; bf16 h[4]; } o;
  o.h[0] = __float2bfloat16(v.x);
  o.h[1] = __float2bfloat16(v.y);
  o.h[2] = __float2bfloat16(v.z);
  o.h[3] = __float2bfloat16(v.w);
  ((ushort4*)out)[i] = o.u;
}

// ---------------------------------------------------------------------------
// Pointwise: a = sigmoid(-gate), v = sigmoid(gate) * g(hidden)
// ---------------------------------------------------------------------------
__device__ __forceinline__ void av_from_gh(float gate, float hid, float& a,
                                           float& v) {
  gate = fminf(fmaxf(gate, -20.f), 20.f);
  float eg = __expf(gate);
  a = 1.f / (1.f + eg);   // sigmoid(-gate) = 1 - z
  float z = eg * a;       // sigmoid(gate)
  float eh = __expf(fminf(fmaxf(hid, -20.f), 0.f));
  float sig = eh / (1.f + eh);
  float gfun = (hid >= 0.f) ? (hid + 0.5f) : sig;
  v = z * gfun;
}

__device__ __forceinline__ unsigned pack_av(float a, float v) {
  union { bf16 h[2]; unsigned u; } o;
  o.h[0] = __float2bfloat16(a);
  o.h[1] = __float2bfloat16(v);
  return o.u;
}

// ---------------------------------------------------------------------------
// Fused GEMM + bias + pointwise + per-chunk scan summaries.
//
// v4:
//  * AV output re-laid-out per-cb dense: AV[cb][row][64 d] u32. The epilogue
//    bounces pk through the (already needed) LDS transpose and stores the
//    64x64 u32 half-tile as fully-coalesced 1KB/wave dwordx4 stores -> each
//    block writes one dense 32KB span (was: scattered dwords, 64B runs at
//    1KB stride; WRITE_SIZE showed 3x amplification).
//  * F32A template restored for layer 0 (reads f32 X directly, converts
//    after ds_read) so the separate X-convert pass disappears.
//  * Counted-vmcnt depth-2 pipeline, XCD-bijective swizzle (unchanged).
//
//   block (cb, bt): rows [bt*128,+128) = 2 scan chunks; paired channels
//   d in [cb*64,+64): GEMM cols = gate d and hidden d+256.
// ---------------------------------------------------------------------------
template <bool F32A>
__global__ __launch_bounds__(256, F32A ? 3 : 5) void gemm_av_fused(
    const void* __restrict__ Xv, const bf16* __restrict__ W,
    const float* __restrict__ bias, unsigned* __restrict__ AV,
    float2* __restrict__ AVs) {
  constexpr int ABY = F32A ? 16384 : 8192;  // A-tile bytes per buffer
  constexpr int NLD = F32A ? 6 : 4;         // loads per stage()
  __shared__ __align__(16) char sm[2 * ABY + 16384];
  char* Ab[2] = {sm, sm + ABY};
  bf16* Bbf[2] = {(bf16*)(sm + 2 * ABY), (bf16*)(sm + 2 * ABY + 8192)};
  unsigned* Ts = (unsigned*)sm;  // post-K-loop overlay: [64 t][TSP] u32

  const int tid = threadIdx.x;
  const int w = tid >> 6;
  const int l = tid & 63;
  const int fl = l & 15;
  const int q = l >> 4;

  // XCD-bijective swizzle: xcd owns lin [xcd*256,+256) = bt in [xcd*64,+64)
  const int id = blockIdx.x;
  const int lin = ((id & 7) << 8) | (id >> 3);
  const int cb = lin & 3;              // paired-channel block 0..3
  const int bt = lin >> 2;             // M-tile 0..511
  const long rowBase = (long)bt * 128;
  const int wrow = (w >> 1) * 64;
  const int wc = (w & 1) * 32;

  const float* Xf = (const float*)Xv;
  const bf16* Xb = (const bf16*)Xv;

  // ---- staging sources (hoisted). LDS chunk L holds k-chunk (L&m)^swz(row)
  const float* aSrcF[4];
  const bf16* aSrcB[2];
  const bf16* bSrc[2];
  int aDstF[4], sDst[2];
  if constexpr (F32A) {
#pragma unroll
    for (int c = 0; c < 4; c++) {
      const int L = c * 256 + tid;
      const int row = L >> 3;                 // 0..127
      const int kc = (L & 7) ^ (row & 7);     // 4-float chunk
      aSrcF[c] = Xf + (rowBase + row) * 256 + kc * 4;
      aDstF[c] = (c * 256 + w * 64) * 16;
    }
  } else {
#pragma unroll
    for (int c = 0; c < 2; c++) {
      const int L = c * 256 + tid;
      const int row = L >> 2;                      // 0..127
      const int kc = (L & 3) ^ ((row >> 1) & 3);   // 8-bf16 chunk
      aSrcB[c] = Xb + (rowBase + row) * 256 + kc * 8;
    }
  }
#pragma unroll
  for (int c = 0; c < 2; c++) {
    const int L = c * 256 + tid;
    const int row = L >> 2;
    const int kc = (L & 3) ^ ((row >> 1) & 3);
    const int grow = (row < 64) ? (cb * 64 + row) : (192 + cb * 64 + row);
    bSrc[c] = W + (long)grow * 256 + kc * 8;
    sDst[c] = (c * 256 + w * 64) * 16;  // wave-uniform base; HW adds lane*16
  }
  auto stage = [&](int bi, int ks) {
    if constexpr (F32A) {
#pragma unroll
      for (int c = 0; c < 4; c++)
        load_lds16(aSrcF[c] + ks * 32, Ab[bi] + aDstF[c]);
    } else {
#pragma unroll
      for (int c = 0; c < 2; c++)
        load_lds16(aSrcB[c] + ks * 32, Ab[bi] + sDst[c]);
    }
#pragma unroll
    for (int c = 0; c < 2; c++)
      load_lds16(bSrc[c] + ks * 32, (char*)Bbf[bi] + sDst[c]);
  };

  // ---- fragment reads (swizzle-matched, conflict-free)
  auto fragA = [&](const char* buf, int mt) -> short8 {
    const int row = wrow + 16 * mt + fl;
    if constexpr (F32A) {
      const float* p = (const float*)buf + row * 32;
      const int k0c = (2 * q) ^ (row & 7);
      const int k1c = (2 * q + 1) ^ (row & 7);
      const float4 u0 = *(const float4*)(p + k0c * 4);
      const float4 u1 = *(const float4*)(p + k1c * 4);
      const float vals[8] = {u0.x, u0.y, u0.z, u0.w, u1.x, u1.y, u1.z, u1.w};
      short8 r;
#pragma unroll
      for (int i = 0; i < 8; i++) {
        union { bf16 h; short s; } t;
        t.h = __float2bfloat16(vals[i]);
        r[i] = t.s;
      }
      return r;
    } else {
      const int kc = q ^ ((row >> 1) & 3);
      return *(const short8*)((const bf16*)buf + row * 32 + kc * 8);
    }
  };
  auto fragB = [&](const bf16* buf, int nt) -> short8 {
    const int row =
        (nt < 2) ? (wc + 16 * nt + fl) : (64 + wc + 16 * (nt - 2) + fl);
    const int kc = q ^ ((row >> 1) & 3);
    return *(const short8*)(buf + row * 32 + kc * 8);
  };

  f32x4 acc[4][4];
#pragma unroll
  for (int i = 0; i < 4; i++)
#pragma unroll
    for (int j = 0; j < 4; j++) acc[i][j] = (f32x4)0.0f;

  // ---- K-loop: depth-2 prefetch, counted vmcnt (never drained in-loop)
  stage(0, 0);
  stage(1, 1);
#pragma unroll
  for (int ks = 0; ks < 8; ks++) {
    const int bi = ks & 1;
    if (ks < 7)
      wait_vmcnt<NLD>();   // own stage-ks (oldest NLD) retired -> LDS written
    else
      wait_vmcnt<0>();     // last tile: drain
    __builtin_amdgcn_s_barrier();          // everyone's stage-ks landed
    __builtin_amdgcn_sched_barrier(0);     // keep ds_reads behind the barrier
    short8 af[4], bf_[4];
#pragma unroll
    for (int mt = 0; mt < 4; mt++) af[mt] = fragA(Ab[bi], mt);
#pragma unroll
    for (int nt = 0; nt < 4; nt++) bf_[nt] = fragB(Bbf[bi], nt);
#pragma unroll
    for (int mt = 0; mt < 4; mt++)
#pragma unroll
      for (int nt = 0; nt < 4; nt++)
        acc[mt][nt] = __builtin_amdgcn_mfma_f32_16x16x32_bf16(
            af[mt], bf_[nt], acc[mt][nt], 0, 0, 0);
    asm volatile("s_waitcnt lgkmcnt(0)" ::: "memory");  // my reads of cur done
    __builtin_amdgcn_s_barrier();                       // all reads of cur done
    __builtin_amdgcn_sched_barrier(0);                  // pin stage after bar
    if (ks < 6) stage(bi, ks + 2);  // overwrite cur buffer for step ks+2
  }

  // ---- Epilogue: bias + pointwise + pack (registers only)
  float bg[2], bh[2];
#pragma unroll
  for (int p = 0; p < 2; p++) {
    const int d = cb * 64 + wc + 16 * p + fl;
    bg[p] = bias[d];
    bh[p] = bias[256 + d];
  }
  unsigned pk[4][2][4];
#pragma unroll
  for (int mt = 0; mt < 4; mt++)
#pragma unroll
    for (int p = 0; p < 2; p++)
#pragma unroll
      for (int r = 0; r < 4; r++) {
        float a, v;
        av_from_gh(acc[mt][p][r] + bg[p], acc[mt][p + 2][r] + bh[p], a, v);
        pk[mt][p][r] = pack_av(a, v);
      }

  // ---- Two 64-row halves through LDS transpose:
  //      dense coalesced AV stores + per-chunk scan summaries
#pragma unroll
  for (int h = 0; h < 2; h++) {
    if ((w >> 1) == h) {
#pragma unroll
      for (int mt = 0; mt < 4; mt++)
#pragma unroll
        for (int p = 0; p < 2; p++)
#pragma unroll
          for (int r = 0; r < 4; r++)
            Ts[(16 * mt + 4 * q + r) * TSP + wc + 16 * p + fl] = pk[mt][p][r];
    }
    __syncthreads();
    // dense AV half-tile: [64 rows][64 d] u32 -> 1KB/wave contiguous stores
    {
      unsigned* dst = AV + ((long)cb * Mm + rowBase + h * 64) * 64;
#pragma unroll
      for (int j = 0; j < 4; j++) {
        const int idx = j * 256 + tid;
        const int t = idx >> 4;
        const int d4 = idx & 15;
        const uint4 val = *(const uint4*)(Ts + t * TSP + d4 * 4);
        *(uint4*)(dst + 4 * idx) = val;
      }
    }
    if (tid < 64) {
      float A = 1.f, H = 0.f;
#pragma unroll 8
      for (int t = 0; t < 64; t++) {
        const unsigned p = Ts[t * TSP + tid];
        const float a = __uint_as_float((p & 0xffffu) << 16);
        const float v = __uint_as_float(p & 0xffff0000u);
        A *= a;
        H = a * H + v;
      }
      const long cg = (long)(bt >> 6) * NCHUNK + ((bt & 63) << 1) + h;
      AVs[cg * 256 + cb * 64 + tid] = make_float2(A, H);
    }
    __syncthreads();
  }
}

// ---------------------------------------------------------------------------
// Final scan. Prologue folds this chunk's prefix from the (L3-hot, 2MB)
// chunk-summary table itself (independent loads, unrolled) -- no separate
// combine kernels. WRITE_BF16 ? bf16 hidden stream : f32 out stream.
// AV layout: [cb][row][64 d] u32 (matches gemm's dense writes).
// ---------------------------------------------------------------------------
template <bool WRITE_BF16>
__global__ __launch_bounds__(256) void scan_final(
    const unsigned* __restrict__ AV, const float2* __restrict__ AVs,
    bf16* __restrict__ OutB, float* __restrict__ OutF,
    float* __restrict__ Hlast) {
  const int d = threadIdx.x;
  const int c = blockIdx.x % NCHUNK;
  const int b = blockIdx.x / NCHUNK;

  float h = 0.5f;  // h0 = g(0) = 0.5
#pragma unroll 4
  for (int j = 0; j < c; j++) {
    const float2 av = AVs[((long)b * NCHUNK + j) * 256 + d];
    h = av.x * h + av.y;
  }

  const long row0 = (long)b * Ss + (long)c * CLEN;
  const unsigned* src = AV + (long)(d >> 6) * Mm * 64 + (d & 63);
  long obase = row0 * 256 + d;
#pragma unroll 8
  for (int t = 0; t < CLEN; t++) {
    const unsigned p = src[(row0 + t) * 64];
    const float a = __uint_as_float((p & 0xffffu) << 16);
    const float v = __uint_as_float(p & 0xffff0000u);
    h = a * h + v;
    if (WRITE_BF16)
      OutB[obase] = __float2bfloat16(h);
    else
      OutF[obase] = h;
    obase += 256;
  }
  if (c == NCHUNK - 1) Hlast[b * 256 + d] = h;
}

// ---------------------------------------------------------------------------
extern "C" void kernel_launch(void* const* d_in, const int* in_sizes, int n_in,
                              void* d_out, int out_size, void* d_ws,
                              size_t ws_size, hipStream_t stream) {
  const float* x = (const float*)d_in[0];
  const float* W0f = (const float*)d_in[1];
  const float* b0 = (const float*)d_in[2];
  const float* W1f = (const float*)d_in[3];
  const float* b1 = (const float*)d_in[4];

  float* outF = (float*)d_out;              // out1 (f32), Mm*256 elements
  float* hlast = outF + (long)Mm * 256;     // h: (2,8,1,256) f32
  // d_out's first 32 MiB doubles as bf16 scratch for X1 (dead before the
  // final f32 out-write overwrites it; ordering is stream-sequential).
  bf16* X1b = (bf16*)d_out;

  char* ws = (char*)d_ws;
  unsigned* AV = (unsigned*)ws;                      // Mm*256 u32 = 64 MiB
  bf16* W0b = (bf16*)(ws + (long)Mm * 256 * 4);      // 512*256 bf16
  bf16* W1b = W0b + (long)Nn * Dd;
  float2* AVs = (float2*)(W1b + (long)Nn * Dd);      // [Bb*NCHUNK][256] = 2 MiB

  const dim3 gemmGrid(2048);  // 1-D, XCD-bijective swizzle decoded in-kernel
  const dim3 blk(256);

  // Convert both weight matrices to bf16 in one launch
  const long n4w = (long)Nn * Dd / 4;
  cvt_weights<<<dim3((2 * n4w + 255) / 256), blk, 0, stream>>>(W0f, W1f, W0b,
                                                               W1b, n4w);

  // Layer 0 (A = f32 x, staged via DMA, converted after ds_read)
  gemm_av_fused<true><<<gemmGrid, blk, 0, stream>>>(x, W0b, b0, AV, AVs);
  scan_final<true><<<dim3(Bb * NCHUNK), blk, 0, stream>>>(AV, AVs, X1b,
                                                          nullptr, hlast);

  // Layer 1 (A = bf16 X1 in d_out scratch)
  gemm_av_fused<false><<<gemmGrid, blk, 0, stream>>>(X1b, W1b, b1, AV, AVs);
  scan_final<false><<<dim3(Bb * NCHUNK), blk, 0, stream>>>(
      AV, AVs, nullptr, outF, hlast + Bb * 256);
}